// Round 11
// baseline (296.582 us; speedup 1.0000x reference)
//
#include <hip/hip_runtime.h>
#include <stdint.h>

#define NB_B 4
#define NN 4096
#define NC 4500
#define NT 128
#define FRAME_K 32
#define FEAT_K 16
#define FE_HID 64
#define FEAT_DIM 128
#define HID 128
#define HIDP (HID + 4)
#define NUM_BLOCKS 4

typedef unsigned long long ull;
typedef __attribute__((ext_vector_type(8))) short bf16x8;   // 8 bf16 (4 VGPRs)
typedef __attribute__((ext_vector_type(4))) float f32x4;    // MFMA C/D

__device__ __forceinline__ ull pack_di(float d, int i) {
    return (((ull)__float_as_uint(d)) << 32) | (uint32_t)(unsigned)i;
}

__device__ __forceinline__ unsigned short f2bf(float f) {  // RNE fp32->bf16
    uint32_t u = __float_as_uint(f);
    return (unsigned short)((u + 0x7fffu + ((u >> 16) & 1u)) >> 16);
}

#define UMIN(a,b) ((a) < (b) ? (a) : (b))

#define INS4(v) do { ull _v=(v); if (_v < t3) { if (_v < t2) { t3=t2; \
    if (_v < t1) { t2=t1; if (_v < t0) { t1=t0; t0=_v; } else t1=_v; } \
    else t2=_v; } else t3=_v; } } while(0)

#define LMIN16(dst, v) do { \
    ull _a0 = UMIN(v[0], v[1]),  _a1 = UMIN(v[2], v[3]); \
    ull _a2 = UMIN(v[4], v[5]),  _a3 = UMIN(v[6], v[7]); \
    ull _a4 = UMIN(v[8], v[9]),  _a5 = UMIN(v[10], v[11]); \
    ull _a6 = UMIN(v[12], v[13]),_a7 = UMIN(v[14], v[15]); \
    ull _b0 = UMIN(_a0, _a1), _b1 = UMIN(_a2, _a3); \
    ull _b2 = UMIN(_a4, _a5), _b3 = UMIN(_a6, _a7); \
    dst = UMIN(UMIN(_b0, _b1), UMIN(_b2, _b3)); \
} while(0)

// ---------------- K0: weight transpose+bf16 cast + clean SoA ---------------
__global__ __launch_bounds__(256) void k_prep(
    const float* __restrict__ W0, const float* __restrict__ W1,
    const float* __restrict__ clean,
    unsigned short* __restrict__ W0T, unsigned short* __restrict__ W1T,
    float2* __restrict__ CXY, float* __restrict__ CZ)
{
    int idx = blockIdx.x * 256 + threadIdx.x;   // 0..65535
    int k = idx & 127, n = (idx >> 7) & 127, blk = idx >> 14;
    int src = blk * 16384 + k * 128 + n;
    W0T[idx] = f2bf(W0[src]);
    W1T[idx] = f2bf(W1[src]);
    if (idx < NB_B * NC) {                      // clean -> SoA (exact copy)
        float x = clean[idx*3+0], y = clean[idx*3+1], z = clean[idx*3+2];
        CXY[idx] = make_float2(x, y);
        CZ[idx]  = z;
    }
}

// ---------------- K1: fused neighbor search + feature net ------------------
__global__ __launch_bounds__(256) void k_nbr(
    const float* __restrict__ pcl, const int* __restrict__ pidx,
    const float* __restrict__ W1, const float* __restrict__ b1,
    const float* __restrict__ W2, const float* __restrict__ b2,
    float* __restrict__ feat_out,
    float* __restrict__ frames, float* __restrict__ framesC)
{
    int blk = blockIdx.x;              // 0..511  (b*128 + i)
    int b = blk >> 7;
    int i = blk & 127;
    int t = threadIdx.x;
    int wave = t >> 6, lane = t & 63;
    __shared__ ull wred[2][4];
    __shared__ float nb[FEAT_K][3];
    __shared__ float hmax[FE_HID];
    const float* P = pcl + b * NN * 3;
    int qi = pidx[i];
    float qx = P[qi*3+0], qy = P[qi*3+1], qz = P[qi*3+2];

    ull v3[16], v2[16];
    #pragma unroll
    for (int c2 = 0; c2 < 16; ++c2) {
        int j = t + c2*256;
        float dx = P[j*3+0]-qx, dy = P[j*3+1]-qy, dz = P[j*3+2]-qz;
        float dd2 = dx*dx + dy*dy;
        v2[c2] = pack_di(dd2, j);
        v3[c2] = pack_di(dd2 + dz*dz, j);
    }

    int mysel3 = 0, mysel2 = 0;

    {   // top-16 on 3D metric
        ull mymin;
        LMIN16(mymin, v3);
        for (int r = 0; r < FEAT_K; ++r) {
            ull wm = mymin;
            for (int mask = 1; mask < 64; mask <<= 1) {
                ull o = __shfl_xor(wm, mask, 64);
                wm = UMIN(wm, o);
            }
            if (lane == 0) wred[r & 1][wave] = wm;
            __syncthreads();
            ull w0 = wred[r&1][0], w1 = wred[r&1][1];
            ull w2 = wred[r&1][2], w3 = wred[r&1][3];
            ull ww = UMIN(UMIN(w0, w1), UMIN(w2, w3));
            if (t == r) mysel3 = (int)(ww & 0xffffffffu);
            if (mymin == ww) {
                #pragma unroll
                for (int c2 = 0; c2 < 16; ++c2)
                    if (v3[c2] == ww) v3[c2] = ~0ull;
                LMIN16(mymin, v3);
            }
        }
    }
    {   // top-32 on 2D metric
        ull mymin;
        LMIN16(mymin, v2);
        for (int r = 0; r < FRAME_K; ++r) {
            ull wm = mymin;
            for (int mask = 1; mask < 64; mask <<= 1) {
                ull o = __shfl_xor(wm, mask, 64);
                wm = UMIN(wm, o);
            }
            if (lane == 0) wred[r & 1][wave] = wm;
            __syncthreads();
            ull w0 = wred[r&1][0], w1 = wred[r&1][1];
            ull w2 = wred[r&1][2], w3 = wred[r&1][3];
            ull ww = UMIN(UMIN(w0, w1), UMIN(w2, w3));
            if (t == r) mysel2 = (int)(ww & 0xffffffffu);
            if (mymin == ww) {
                #pragma unroll
                for (int c2 = 0; c2 < 16; ++c2)
                    if (v2[c2] == ww) v2[c2] = ~0ull;
                LMIN16(mymin, v2);
            }
        }
    }

    if (t < FRAME_K) {
        int j = mysel2;
        float fx = P[j*3+0], fy = P[j*3+1], fz = P[j*3+2];
        int o = (blk*FRAME_K + t)*3;
        frames[o+0] = fx; frames[o+1] = fy; frames[o+2] = fz;
        framesC[o+0] = fx-qx; framesC[o+1] = fy-qy; framesC[o+2] = fz-qz;
    }
    if (t < FEAT_K) {
        int j = mysel3;
        nb[t][0] = P[j*3+0]; nb[t][1] = P[j*3+1]; nb[t][2] = P[j*3+2];
    }
    __syncthreads();
    if (t < FE_HID) {
        float base = b1[t] + qx*W1[0*FE_HID+t] + qy*W1[1*FE_HID+t] + qz*W1[2*FE_HID+t];
        float w3 = W1[3*FE_HID+t], w4 = W1[4*FE_HID+t], w5 = W1[5*FE_HID+t];
        float mv = 0.0f;
        #pragma unroll
        for (int j = 0; j < FEAT_K; ++j) {
            float pre = base + (nb[j][0]-qx)*w3 + (nb[j][1]-qy)*w4 + (nb[j][2]-qz)*w5;
            pre = fmaxf(pre, 0.0f);
            mv = fmaxf(mv, pre);
        }
        hmax[t] = mv;
    }
    __syncthreads();
    if (t < FEAT_DIM) {
        float a0 = 0.f, a1 = 0.f, a2 = 0.f, a3 = 0.f;
        #pragma unroll
        for (int u = 0; u < FE_HID; u += 4) {
            a0 += hmax[u+0] * W2[(u+0)*FEAT_DIM + t];
            a1 += hmax[u+1] * W2[(u+1)*FEAT_DIM + t];
            a2 += hmax[u+2] * W2[(u+2)*FEAT_DIM + t];
            a3 += hmax[u+3] * W2[(u+3)*FEAT_DIM + t];
        }
        float acc = b2[t] + (a0 + a1) + (a2 + a3);
        feat_out[blk*FEAT_DIM + t] = fmaxf(acc, 0.0f);
    }
}

// ---------------- K2: clean KNN (2D, k=4) -> grad_target -------------------
// 8 lanes per query (8 queries/wave).  SoA float2 loads (group-broadcast),
// f32 threshold fast-guard; packed u64 insert only inside the guard so
// tie-breaking stays bit-identical to jax.lax.top_k.
__global__ __launch_bounds__(256) void k_clean(
    const float2* __restrict__ CXY, const float* __restrict__ CZ,
    const float* __restrict__ frames, float* __restrict__ gt)
{
    int t = threadIdx.x;
    int wave = t >> 6, lane = t & 63;
    int g = lane >> 3, sl = lane & 7;
    int qid = blockIdx.x * 32 + wave * 8 + g;   // 0..16383
    int m = qid >> 5;
    int b = m >> 7;
    const float2* Cxy = CXY + b * NC;
    const float* Cz  = CZ  + b * NC;
    float qx = frames[qid*3+0], qy = frames[qid*3+1], qz = frames[qid*3+2];

    const ull SENT = (((ull)0x7F800000u) << 32) | 0xFFFFFFFFu;  // (+INF, idxmax)
    ull t0=SENT, t1=SENT, t2=SENT, t3=SENT;
    float th3 = __builtin_inff();

    for (int j = sl; j < NC; j += 8) {
        float2 p = Cxy[j];
        float dx = p.x - qx, dy = p.y - qy;
        float d = dx*dx + dy*dy;
        if (d <= th3) {                 // <=: ties fall through to exact packed compare
            ull v = pack_di(d, j);
            INS4(v);
            th3 = __uint_as_float((uint32_t)(t3 >> 32));
        }
    }
    // butterfly merge across the 8-lane group
    for (int mask = 1; mask < 8; mask <<= 1) {
        ull e0 = __shfl_xor(t0, mask, 64);
        ull e1 = __shfl_xor(t1, mask, 64);
        ull e2 = __shfl_xor(t2, mask, 64);
        ull e3 = __shfl_xor(t3, mask, 64);
        INS4(e0); INS4(e1); INS4(e2); INS4(e3);
    }
    if (sl == 0) {
        int i0 = (int)(t0 & 0xffffffffu);
        int i1 = (int)(t1 & 0xffffffffu);
        int i2 = (int)(t2 & 0xffffffffu);
        int i3 = (int)(t3 & 0xffffffffu);
        float mz = 0.25f * (Cz[i0] + Cz[i1] + Cz[i2] + Cz[i3]);
        gt[qid] = mz - qz;       // grad_target = -(frame_z - mean(clean_z))
    }
}

// ---------------- K3: score net via MFMA + per-block loss partial ----------
__global__ __launch_bounds__(512, 4) void k_score(
    const float* __restrict__ feat, const float* __restrict__ xc,
    const float* __restrict__ gtv,
    const unsigned short* __restrict__ W0T, const unsigned short* __restrict__ W1T,
    const float* __restrict__ Wp, const float* __restrict__ bp,
    const float* __restrict__ g0, const float* __restrict__ b0,
    const float* __restrict__ bf0,
    const float* __restrict__ g1, const float* __restrict__ b1,
    const float* __restrict__ bf1,
    const float* __restrict__ Wc, const float* __restrict__ bc,
    const float* __restrict__ gO, const float* __restrict__ bO,
    const float* __restrict__ Wo, const float* __restrict__ bo,
    float* __restrict__ loss_part)
{
    int m = blockIdx.x;                // 0..511
    int t = threadIdx.x;               // 0..511
    int c = t & 127, q = t >> 7;
    int w = t >> 6;
    int l = t & 63;
    int l15 = l & 15, lg = l >> 4;
    int col = w * 16 + l15;

    __shared__ float cf[FEAT_DIM];
    __shared__ float xs[FRAME_K][3];
    __shared__ float sh[HID];
    __shared__ float ccs[NUM_BLOCKS][HID];
    __shared__ unsigned short Abuf[FRAME_K * HID];   // 8KB bf16, swizzled
    __shared__ float actO[FRAME_K][HIDP];
    __shared__ float rsum[FRAME_K];

    if (t < FEAT_DIM) cf[t] = feat[m*FEAT_DIM + t];
    else if (t >= 128 && t < 128 + FRAME_K) {
        int r = t - 128;
        xs[r][0] = xc[(m*FRAME_K+r)*3+0];
        xs[r][1] = xc[(m*FRAME_K+r)*3+1];
        xs[r][2] = xc[(m*FRAME_K+r)*3+2];
    }
    __syncthreads();
    {   // residual dots cf.Wc[q] (fp32, exact)
        const float* Wcp = Wc + q*(FEAT_DIM+3)*HID;
        float c0 = 0.f, c1 = 0.f, c2 = 0.f, c3 = 0.f;
        #pragma unroll 8
        for (int d = 0; d < FEAT_DIM; d += 4) {
            c0 += cf[d+0] * Wcp[(3+d+0)*HID + c];
            c1 += cf[d+1] * Wcp[(3+d+1)*HID + c];
            c2 += cf[d+2] * Wcp[(3+d+2)*HID + c];
            c3 += cf[d+3] * Wcp[(3+d+3)*HID + c];
        }
        ccs[q][c] = bc[q*HID + c] + (c0 + c1) + (c2 + c3);
    }
    if (q == 0) {
        float a0 = 0.f, a1 = 0.f, a2 = 0.f, a3 = 0.f;
        #pragma unroll 8
        for (int d = 0; d < FEAT_DIM; d += 4) {
            a0 += cf[d+0] * Wp[(3+d+0)*HID + c];
            a1 += cf[d+1] * Wp[(3+d+1)*HID + c];
            a2 += cf[d+2] * Wp[(3+d+2)*HID + c];
            a3 += cf[d+3] * Wp[(3+d+3)*HID + c];
        }
        sh[c] = bp[c] + (a0 + a1) + (a2 + a3);
    }
    __syncthreads();

    float net[2][4];
    {
        float wp0 = Wp[0*HID+col], wp1 = Wp[1*HID+col], wp2 = Wp[2*HID+col];
        float s = sh[col];
        #pragma unroll
        for (int mt = 0; mt < 2; ++mt)
            #pragma unroll
            for (int r = 0; r < 4; ++r) {
                int row = mt*16 + lg*4 + r;
                net[mt][r] = s + xs[row][0]*wp0 + xs[row][1]*wp1 + xs[row][2]*wp2;
            }
    }

    for (int blk = 0; blk < NUM_BLOCKS; ++blk) {
        float g0c = g0[blk*HID+col], b0c = b0[blk*HID+col], bf0c = bf0[blk*HID+col];
        float g1c = g1[blk*HID+col], b1c = b1[blk*HID+col], bf1c = bf1[blk*HID+col];

        #pragma unroll
        for (int mt = 0; mt < 2; ++mt)
            #pragma unroll
            for (int r = 0; r < 4; ++r) {
                int row = mt*16 + lg*4 + r;
                float a = fmaxf(net[mt][r]*g0c + b0c, 0.0f);
                int byte = row*256 + ((col*2) ^ ((row&7)<<4));
                *(unsigned short*)((char*)Abuf + byte) = f2bf(a);
            }
        __syncthreads();

        f32x4 acc[2];
        acc[0] = (f32x4){bf0c, bf0c, bf0c, bf0c};
        acc[1] = (f32x4){bf0c, bf0c, bf0c, bf0c};
        const unsigned short* B0 = W0T + blk*HID*HID + col*HID;
        #pragma unroll
        for (int kt = 0; kt < 4; ++kt) {
            int k0 = kt*32 + lg*8;
            bf16x8 bfrag = *(const bf16x8*)(B0 + k0);
            #pragma unroll
            for (int mt = 0; mt < 2; ++mt) {
                int row = mt*16 + l15;
                int byte = row*256 + ((k0*2) ^ ((row&7)<<4));
                bf16x8 afrag = *(bf16x8*)((char*)Abuf + byte);
                acc[mt] = __builtin_amdgcn_mfma_f32_16x16x32_bf16(afrag, bfrag, acc[mt], 0, 0, 0);
            }
        }
        __syncthreads();

        #pragma unroll
        for (int mt = 0; mt < 2; ++mt)
            #pragma unroll
            for (int r = 0; r < 4; ++r) {
                int row = mt*16 + lg*4 + r;
                float a = fmaxf(acc[mt][r]*g1c + b1c, 0.0f);
                int byte = row*256 + ((col*2) ^ ((row&7)<<4));
                *(unsigned short*)((char*)Abuf + byte) = f2bf(a);
            }
        __syncthreads();

        f32x4 dacc[2];
        dacc[0] = (f32x4){bf1c, bf1c, bf1c, bf1c};
        dacc[1] = (f32x4){bf1c, bf1c, bf1c, bf1c};
        const unsigned short* B1 = W1T + blk*HID*HID + col*HID;
        #pragma unroll
        for (int kt = 0; kt < 4; ++kt) {
            int k0 = kt*32 + lg*8;
            bf16x8 bfrag = *(const bf16x8*)(B1 + k0);
            #pragma unroll
            for (int mt = 0; mt < 2; ++mt) {
                int row = mt*16 + l15;
                int byte = row*256 + ((k0*2) ^ ((row&7)<<4));
                bf16x8 afrag = *(bf16x8*)((char*)Abuf + byte);
                dacc[mt] = __builtin_amdgcn_mfma_f32_16x16x32_bf16(afrag, bfrag, dacc[mt], 0, 0, 0);
            }
        }
        __syncthreads();

        const float* Wcp = Wc + blk*(FEAT_DIM+3)*HID;
        float wc0 = Wcp[0*HID+col], wc1 = Wcp[1*HID+col], wc2 = Wcp[2*HID+col];
        float ccv = ccs[blk][col];
        #pragma unroll
        for (int mt = 0; mt < 2; ++mt)
            #pragma unroll
            for (int r = 0; r < 4; ++r) {
                int row = mt*16 + lg*4 + r;
                net[mt][r] += dacc[mt][r] + xs[row][0]*wc0 + xs[row][1]*wc1
                              + xs[row][2]*wc2 + ccv;
            }
    }

    {
        float gc = gO[col], bcv = bO[col], wo = Wo[col];
        #pragma unroll
        for (int mt = 0; mt < 2; ++mt)
            #pragma unroll
            for (int r = 0; r < 4; ++r) {
                int row = mt*16 + lg*4 + r;
                actO[row][col] = fmaxf(net[mt][r]*gc + bcv, 0.0f) * wo;
            }
    }
    __syncthreads();
    if (t < FRAME_K) {
        float s = 0.0f;
        for (int d = 0; d < HID; d += 4) {
            float4 a4 = *reinterpret_cast<const float4*>(&actO[t][d]);
            s += a4.x + a4.y + a4.z + a4.w;
        }
        float gp = s + bo[0];
        float e = gtv[m*FRAME_K + t] - gp;
        rsum[t] = e*e;
    }
    __syncthreads();
    if (t == 0) {
        float s = 0.0f;
        #pragma unroll
        for (int j = 0; j < FRAME_K; ++j) s += rsum[j];
        loss_part[m] = s;
    }
}

// ---------------- K4: final reduction -------------------------------------
__global__ __launch_bounds__(256) void k_loss(
    const float* __restrict__ lp, float* __restrict__ out)
{
    __shared__ float red[256];
    int t = threadIdx.x;
    red[t] = lp[t] + lp[t+256];
    __syncthreads();
    for (int s = 128; s > 0; s >>= 1) {
        if (t < s) red[t] += red[t+s];
        __syncthreads();
    }
    if (t == 0) out[0] = red[0] * (50.0f / 16384.0f);
}

extern "C" void kernel_launch(void* const* d_in, const int* in_sizes, int n_in,
                              void* d_out, int out_size, void* d_ws, size_t ws_size,
                              hipStream_t stream)
{
    (void)in_sizes; (void)n_in; (void)out_size; (void)ws_size;
    const float* pcl_noisy = (const float*)d_in[0];
    const float* pcl_clean = (const float*)d_in[1];
    const int*   pnt_idx   = (const int*)d_in[2];
    const float* feW1 = (const float*)d_in[3];
    const float* feb1 = (const float*)d_in[4];
    const float* feW2 = (const float*)d_in[5];
    const float* feb2 = (const float*)d_in[6];
    const float* Wp  = (const float*)d_in[7];
    const float* bp  = (const float*)d_in[8];
    const float* g0  = (const float*)d_in[9];
    const float* b0  = (const float*)d_in[10];
    const float* W0  = (const float*)d_in[11];
    const float* bf0 = (const float*)d_in[12];
    const float* g1  = (const float*)d_in[13];
    const float* b1  = (const float*)d_in[14];
    const float* W1  = (const float*)d_in[15];
    const float* bf1 = (const float*)d_in[16];
    const float* Wc  = (const float*)d_in[17];
    const float* bc  = (const float*)d_in[18];
    const float* gO  = (const float*)d_in[19];
    const float* bO  = (const float*)d_in[20];
    const float* Wo  = (const float*)d_in[21];
    const float* bo  = (const float*)d_in[22];

    float* ws = (float*)d_ws;
    float* feat    = ws;                       // 65536 floats
    float* frames  = ws + 65536;               // 49152
    float* framesC = ws + 65536 + 49152;       // 49152
    float* gt      = ws + 163840;              // 16384
    float* lp      = ws + 180224;              // 512
    unsigned short* W0T = (unsigned short*)(ws + 180736);            // 65536 u16 (32768 floats)
    unsigned short* W1T = (unsigned short*)(ws + 180736 + 32768);    // 65536 u16
    float2* CXY = (float2*)(ws + 246272);      // 18000 float2 (36000 floats)
    float*  CZ  = ws + 282272;                 // 18000 floats -> ends 300272

    k_prep  <<<256, 256, 0, stream>>>(W0, W1, pcl_clean, W0T, W1T, CXY, CZ);
    k_nbr   <<<512, 256, 0, stream>>>(pcl_noisy, pnt_idx, feW1, feb1, feW2, feb2,
                                      feat, frames, framesC);
    k_clean <<<512, 256, 0, stream>>>(CXY, CZ, frames, gt);
    k_score <<<512, 512, 0, stream>>>(feat, framesC, gt, W0T, W1T,
                                      Wp, bp, g0, b0, bf0, g1, b1, bf1,
                                      Wc, bc, gO, bO, Wo, bo, lp);
    k_loss  <<<1, 256, 0, stream>>>(lp, (float*)d_out);
}

// Round 15
// 235.544 us; speedup vs baseline: 1.2591x; 1.2591x over previous
//
#include <hip/hip_runtime.h>
#include <stdint.h>

#define NB_B 4
#define NN 4096
#define NC 4500
#define NT 128
#define FRAME_K 32
#define FEAT_K 16
#define FE_HID 64
#define FEAT_DIM 128
#define HID 128
#define HIDP (HID + 4)
#define NUM_BLOCKS 4

typedef unsigned long long ull;
typedef __attribute__((ext_vector_type(8))) short bf16x8;   // 8 bf16 (4 VGPRs)
typedef __attribute__((ext_vector_type(4))) float f32x4;    // MFMA C/D

__device__ __forceinline__ ull pack_di(float d, int i) {
    return (((ull)__float_as_uint(d)) << 32) | (uint32_t)(unsigned)i;
}

__device__ __forceinline__ unsigned short f2bf(float f) {  // RNE fp32->bf16
    uint32_t u = __float_as_uint(f);
    return (unsigned short)((u + 0x7fffu + ((u >> 16) & 1u)) >> 16);
}

#define UMIN(a,b) ((a) < (b) ? (a) : (b))

// generic 4-deep packed insert on named slots
#define INS4G(a0,a1,a2,a3,v) do { ull _v=(v); if (_v < a3) { if (_v < a2) { a3=a2; \
    if (_v < a1) { a2=a1; if (_v < a0) { a1=a0; a0=_v; } else a1=_v; } \
    else a2=_v; } else a3=_v; } } while(0)

#define INS4(v) INS4G(t0,t1,t2,t3,v)

#define LMIN16(dst, v) do { \
    ull _a0 = UMIN(v[0], v[1]),  _a1 = UMIN(v[2], v[3]); \
    ull _a2 = UMIN(v[4], v[5]),  _a3 = UMIN(v[6], v[7]); \
    ull _a4 = UMIN(v[8], v[9]),  _a5 = UMIN(v[10], v[11]); \
    ull _a6 = UMIN(v[12], v[13]),_a7 = UMIN(v[14], v[15]); \
    ull _b0 = UMIN(_a0, _a1), _b1 = UMIN(_a2, _a3); \
    ull _b2 = UMIN(_a4, _a5), _b3 = UMIN(_a6, _a7); \
    dst = UMIN(UMIN(_b0, _b1), UMIN(_b2, _b3)); \
} while(0)

// ---------------- K0: weight transpose+bf16 cast + clean SoA ---------------
__global__ __launch_bounds__(256) void k_prep(
    const float* __restrict__ W0, const float* __restrict__ W1,
    const float* __restrict__ clean,
    unsigned short* __restrict__ W0T, unsigned short* __restrict__ W1T,
    float2* __restrict__ CXY, float* __restrict__ CZ)
{
    int idx = blockIdx.x * 256 + threadIdx.x;   // 0..65535
    int k = idx & 127, n = (idx >> 7) & 127, blk = idx >> 14;
    int src = blk * 16384 + k * 128 + n;
    W0T[idx] = f2bf(W0[src]);
    W1T[idx] = f2bf(W1[src]);
    if (idx < NB_B * NC) {                      // clean -> SoA (exact copy)
        float x = clean[idx*3+0], y = clean[idx*3+1], z = clean[idx*3+2];
        CXY[idx] = make_float2(x, y);
        CZ[idx]  = z;
    }
}

// ---------------- K1: fused neighbor search + feature net ------------------
// Register-resident candidates; the two independent top-k selections (3D k=16,
// 2D k=32) run FUSED in one 32-round loop: 32 barriers instead of 48, and the
// two shuffle-reduce chains interleave (ILP).  Selection order bit-identical
// to jax.lax.top_k (packed (dist,idx) lexicographic).
__global__ __launch_bounds__(256) void k_nbr(
    const float* __restrict__ pcl, const int* __restrict__ pidx,
    const float* __restrict__ W1, const float* __restrict__ b1,
    const float* __restrict__ W2, const float* __restrict__ b2,
    float* __restrict__ feat_out,
    float* __restrict__ frames, float* __restrict__ framesC)
{
    int blk = blockIdx.x;              // 0..511  (b*128 + i)
    int b = blk >> 7;
    int i = blk & 127;
    int t = threadIdx.x;
    int wave = t >> 6, lane = t & 63;
    __shared__ ull wred3[2][4];
    __shared__ ull wred2[2][4];
    __shared__ float nb[FEAT_K][3];
    __shared__ float hmax[FE_HID];
    const float* P = pcl + b * NN * 3;
    int qi = pidx[i];
    float qx = P[qi*3+0], qy = P[qi*3+1], qz = P[qi*3+2];

    ull v3[16], v2[16];
    #pragma unroll
    for (int c2 = 0; c2 < 16; ++c2) {
        int j = t + c2*256;
        float dx = P[j*3+0]-qx, dy = P[j*3+1]-qy, dz = P[j*3+2]-qz;
        float dd2 = dx*dx + dy*dy;
        v2[c2] = pack_di(dd2, j);
        v3[c2] = pack_di(dd2 + dz*dz, j);
    }

    int mysel3 = 0, mysel2 = 0;
    ull mymin3, mymin2;
    LMIN16(mymin3, v3);
    LMIN16(mymin2, v2);

    for (int r = 0; r < FRAME_K; ++r) {
        // wave-reduce both metrics (independent chains -> ILP)
        ull wm2 = mymin2;
        for (int mask = 1; mask < 64; mask <<= 1) {
            ull o = __shfl_xor(wm2, mask, 64);
            wm2 = UMIN(wm2, o);
        }
        if (r < FEAT_K) {
            ull wm3 = mymin3;
            for (int mask = 1; mask < 64; mask <<= 1) {
                ull o = __shfl_xor(wm3, mask, 64);
                wm3 = UMIN(wm3, o);
            }
            if (lane == 0) wred3[r & 1][wave] = wm3;
        }
        if (lane == 0) wred2[r & 1][wave] = wm2;
        __syncthreads();
        {   // 2D selection (all 32 rounds)
            ull w0 = wred2[r&1][0], w1 = wred2[r&1][1];
            ull w2 = wred2[r&1][2], w3 = wred2[r&1][3];
            ull ww = UMIN(UMIN(w0, w1), UMIN(w2, w3));
            if (t == r) mysel2 = (int)(ww & 0xffffffffu);
            if (mymin2 == ww) {
                #pragma unroll
                for (int c2 = 0; c2 < 16; ++c2)
                    if (v2[c2] == ww) v2[c2] = ~0ull;
                LMIN16(mymin2, v2);
            }
        }
        if (r < FEAT_K) {   // 3D selection (first 16 rounds)
            ull w0 = wred3[r&1][0], w1 = wred3[r&1][1];
            ull w2 = wred3[r&1][2], w3 = wred3[r&1][3];
            ull ww = UMIN(UMIN(w0, w1), UMIN(w2, w3));
            if (t == r) mysel3 = (int)(ww & 0xffffffffu);
            if (mymin3 == ww) {
                #pragma unroll
                for (int c2 = 0; c2 < 16; ++c2)
                    if (v3[c2] == ww) v3[c2] = ~0ull;
                LMIN16(mymin3, v3);
            }
        }
    }

    if (t < FRAME_K) {
        int j = mysel2;
        float fx = P[j*3+0], fy = P[j*3+1], fz = P[j*3+2];
        int o = (blk*FRAME_K + t)*3;
        frames[o+0] = fx; frames[o+1] = fy; frames[o+2] = fz;
        framesC[o+0] = fx-qx; framesC[o+1] = fy-qy; framesC[o+2] = fz-qz;
    }
    if (t < FEAT_K) {
        int j = mysel3;
        nb[t][0] = P[j*3+0]; nb[t][1] = P[j*3+1]; nb[t][2] = P[j*3+2];
    }
    __syncthreads();
    if (t < FE_HID) {
        float base = b1[t] + qx*W1[0*FE_HID+t] + qy*W1[1*FE_HID+t] + qz*W1[2*FE_HID+t];
        float w3 = W1[3*FE_HID+t], w4 = W1[4*FE_HID+t], w5 = W1[5*FE_HID+t];
        float mv = 0.0f;
        #pragma unroll
        for (int j = 0; j < FEAT_K; ++j) {
            float pre = base + (nb[j][0]-qx)*w3 + (nb[j][1]-qy)*w4 + (nb[j][2]-qz)*w5;
            pre = fmaxf(pre, 0.0f);
            mv = fmaxf(mv, pre);
        }
        hmax[t] = mv;
    }
    __syncthreads();
    if (t < FEAT_DIM) {
        float a0 = 0.f, a1 = 0.f, a2 = 0.f, a3 = 0.f;
        #pragma unroll
        for (int u = 0; u < FE_HID; u += 4) {
            a0 += hmax[u+0] * W2[(u+0)*FEAT_DIM + t];
            a1 += hmax[u+1] * W2[(u+1)*FEAT_DIM + t];
            a2 += hmax[u+2] * W2[(u+2)*FEAT_DIM + t];
            a3 += hmax[u+3] * W2[(u+3)*FEAT_DIM + t];
        }
        float acc = b2[t] + (a0 + a1) + (a2 + a3);
        feat_out[blk*FEAT_DIM + t] = fmaxf(acc, 0.0f);
    }
}

// ---------------- K2: clean KNN (2D, k=4) -> grad_target -------------------
// R8 structure (1 query/wave, 64 lanes, 4096 blocks — measured 80us) plus:
// SoA float2 loads and TWO independent insert chains per lane (ILP), merged
// exactly.  Selection bit-identical to jax.lax.top_k (packed compares).
__global__ __launch_bounds__(256) void k_clean(
    const float2* __restrict__ CXY, const float* __restrict__ CZ,
    const float* __restrict__ frames, float* __restrict__ gt)
{
    int wave = threadIdx.x >> 6;
    int lane = threadIdx.x & 63;
    int qid = blockIdx.x * 4 + wave;   // 0..16383
    int m = qid >> 5;
    int b = m >> 7;
    const float2* Cxy = CXY + b * NC;
    const float*  Cz  = CZ  + b * NC;
    float qx = frames[qid*3+0], qy = frames[qid*3+1], qz = frames[qid*3+2];

    const ull SENT = (((ull)0x7F800000u) << 32) | 0xFFFFFFFFu;  // (+INF, idxmax)
    ull t0=SENT, t1=SENT, t2=SENT, t3=SENT;      // chain A
    ull s0=SENT, s1=SENT, s2=SENT, s3=SENT;      // chain B

    int j = lane;
    for (; j + 64 < NC; j += 128) {              // 2 points/iter, indep chains
        float2 p1 = Cxy[j];
        float2 p2 = Cxy[j + 64];
        float dx1 = p1.x - qx, dy1 = p1.y - qy;
        float dx2 = p2.x - qx, dy2 = p2.y - qy;
        float d1 = dx1*dx1 + dy1*dy1;
        float d2 = dx2*dx2 + dy2*dy2;
        ull v1 = pack_di(d1, j);
        ull v2 = pack_di(d2, j + 64);
        INS4G(t0,t1,t2,t3, v1);
        INS4G(s0,s1,s2,s3, v2);
    }
    for (; j < NC; j += 64) {                    // tail
        float2 p = Cxy[j];
        float dx = p.x - qx, dy = p.y - qy;
        float d = dx*dx + dy*dy;
        ull v = pack_di(d, j);
        INS4G(t0,t1,t2,t3, v);
    }
    // exact merge of chain B into A (s0<=s1<=s2<=s3)
    INS4(s0); INS4(s1); INS4(s2); INS4(s3);

    // wave butterfly merge
    for (int mask = 1; mask < 64; mask <<= 1) {
        ull e0 = __shfl_xor(t0, mask, 64);
        ull e1 = __shfl_xor(t1, mask, 64);
        ull e2 = __shfl_xor(t2, mask, 64);
        ull e3 = __shfl_xor(t3, mask, 64);
        INS4(e0); INS4(e1); INS4(e2); INS4(e3);
    }
    if (lane == 0) {
        int i0 = (int)(t0 & 0xffffffffu);
        int i1 = (int)(t1 & 0xffffffffu);
        int i2 = (int)(t2 & 0xffffffffu);
        int i3 = (int)(t3 & 0xffffffffu);
        float mz = 0.25f * (Cz[i0] + Cz[i1] + Cz[i2] + Cz[i3]);
        gt[qid] = mz - qz;       // grad_target = -(frame_z - mean(clean_z))
    }
}

// ---------------- K3: score net via MFMA + per-block loss partial ----------
__global__ __launch_bounds__(512, 4) void k_score(
    const float* __restrict__ feat, const float* __restrict__ xc,
    const float* __restrict__ gtv,
    const unsigned short* __restrict__ W0T, const unsigned short* __restrict__ W1T,
    const float* __restrict__ Wp, const float* __restrict__ bp,
    const float* __restrict__ g0, const float* __restrict__ b0,
    const float* __restrict__ bf0,
    const float* __restrict__ g1, const float* __restrict__ b1,
    const float* __restrict__ bf1,
    const float* __restrict__ Wc, const float* __restrict__ bc,
    const float* __restrict__ gO, const float* __restrict__ bO,
    const float* __restrict__ Wo, const float* __restrict__ bo,
    float* __restrict__ loss_part)
{
    int m = blockIdx.x;                // 0..511
    int t = threadIdx.x;               // 0..511
    int c = t & 127, q = t >> 7;
    int w = t >> 6;
    int l = t & 63;
    int l15 = l & 15, lg = l >> 4;
    int col = w * 16 + l15;

    __shared__ float cf[FEAT_DIM];
    __shared__ float xs[FRAME_K][3];
    __shared__ float sh[HID];
    __shared__ float ccs[NUM_BLOCKS][HID];
    __shared__ unsigned short Abuf[FRAME_K * HID];   // 8KB bf16, swizzled
    __shared__ float actO[FRAME_K][HIDP];
    __shared__ float rsum[FRAME_K];

    if (t < FEAT_DIM) cf[t] = feat[m*FEAT_DIM + t];
    else if (t >= 128 && t < 128 + FRAME_K) {
        int r = t - 128;
        xs[r][0] = xc[(m*FRAME_K+r)*3+0];
        xs[r][1] = xc[(m*FRAME_K+r)*3+1];
        xs[r][2] = xc[(m*FRAME_K+r)*3+2];
    }
    __syncthreads();
    {   // residual dots cf.Wc[q] (fp32, exact)
        const float* Wcp = Wc + q*(FEAT_DIM+3)*HID;
        float c0 = 0.f, c1 = 0.f, c2 = 0.f, c3 = 0.f;
        #pragma unroll 8
        for (int d = 0; d < FEAT_DIM; d += 4) {
            c0 += cf[d+0] * Wcp[(3+d+0)*HID + c];
            c1 += cf[d+1] * Wcp[(3+d+1)*HID + c];
            c2 += cf[d+2] * Wcp[(3+d+2)*HID + c];
            c3 += cf[d+3] * Wcp[(3+d+3)*HID + c];
        }
        ccs[q][c] = bc[q*HID + c] + (c0 + c1) + (c2 + c3);
    }
    if (q == 0) {
        float a0 = 0.f, a1 = 0.f, a2 = 0.f, a3 = 0.f;
        #pragma unroll 8
        for (int d = 0; d < FEAT_DIM; d += 4) {
            a0 += cf[d+0] * Wp[(3+d+0)*HID + c];
            a1 += cf[d+1] * Wp[(3+d+1)*HID + c];
            a2 += cf[d+2] * Wp[(3+d+2)*HID + c];
            a3 += cf[d+3] * Wp[(3+d+3)*HID + c];
        }
        sh[c] = bp[c] + (a0 + a1) + (a2 + a3);
    }
    __syncthreads();

    float net[2][4];
    {
        float wp0 = Wp[0*HID+col], wp1 = Wp[1*HID+col], wp2 = Wp[2*HID+col];
        float s = sh[col];
        #pragma unroll
        for (int mt = 0; mt < 2; ++mt)
            #pragma unroll
            for (int r = 0; r < 4; ++r) {
                int row = mt*16 + lg*4 + r;
                net[mt][r] = s + xs[row][0]*wp0 + xs[row][1]*wp1 + xs[row][2]*wp2;
            }
    }

    for (int blk = 0; blk < NUM_BLOCKS; ++blk) {
        float g0c = g0[blk*HID+col], b0c = b0[blk*HID+col], bf0c = bf0[blk*HID+col];
        float g1c = g1[blk*HID+col], b1c = b1[blk*HID+col], bf1c = bf1[blk*HID+col];

        #pragma unroll
        for (int mt = 0; mt < 2; ++mt)
            #pragma unroll
            for (int r = 0; r < 4; ++r) {
                int row = mt*16 + lg*4 + r;
                float a = fmaxf(net[mt][r]*g0c + b0c, 0.0f);
                int byte = row*256 + ((col*2) ^ ((row&7)<<4));
                *(unsigned short*)((char*)Abuf + byte) = f2bf(a);
            }
        __syncthreads();

        f32x4 acc[2];
        acc[0] = (f32x4){bf0c, bf0c, bf0c, bf0c};
        acc[1] = (f32x4){bf0c, bf0c, bf0c, bf0c};
        const unsigned short* B0 = W0T + blk*HID*HID + col*HID;
        #pragma unroll
        for (int kt = 0; kt < 4; ++kt) {
            int k0 = kt*32 + lg*8;
            bf16x8 bfrag = *(const bf16x8*)(B0 + k0);
            #pragma unroll
            for (int mt = 0; mt < 2; ++mt) {
                int row = mt*16 + l15;
                int byte = row*256 + ((k0*2) ^ ((row&7)<<4));
                bf16x8 afrag = *(bf16x8*)((char*)Abuf + byte);
                acc[mt] = __builtin_amdgcn_mfma_f32_16x16x32_bf16(afrag, bfrag, acc[mt], 0, 0, 0);
            }
        }
        __syncthreads();

        #pragma unroll
        for (int mt = 0; mt < 2; ++mt)
            #pragma unroll
            for (int r = 0; r < 4; ++r) {
                int row = mt*16 + lg*4 + r;
                float a = fmaxf(acc[mt][r]*g1c + b1c, 0.0f);
                int byte = row*256 + ((col*2) ^ ((row&7)<<4));
                *(unsigned short*)((char*)Abuf + byte) = f2bf(a);
            }
        __syncthreads();

        f32x4 dacc[2];
        dacc[0] = (f32x4){bf1c, bf1c, bf1c, bf1c};
        dacc[1] = (f32x4){bf1c, bf1c, bf1c, bf1c};
        const unsigned short* B1 = W1T + blk*HID*HID + col*HID;
        #pragma unroll
        for (int kt = 0; kt < 4; ++kt) {
            int k0 = kt*32 + lg*8;
            bf16x8 bfrag = *(const bf16x8*)(B1 + k0);
            #pragma unroll
            for (int mt = 0; mt < 2; ++mt) {
                int row = mt*16 + l15;
                int byte = row*256 + ((k0*2) ^ ((row&7)<<4));
                bf16x8 afrag = *(bf16x8*)((char*)Abuf + byte);
                dacc[mt] = __builtin_amdgcn_mfma_f32_16x16x32_bf16(afrag, bfrag, dacc[mt], 0, 0, 0);
            }
        }
        __syncthreads();

        const float* Wcp = Wc + blk*(FEAT_DIM+3)*HID;
        float wc0 = Wcp[0*HID+col], wc1 = Wcp[1*HID+col], wc2 = Wcp[2*HID+col];
        float ccv = ccs[blk][col];
        #pragma unroll
        for (int mt = 0; mt < 2; ++mt)
            #pragma unroll
            for (int r = 0; r < 4; ++r) {
                int row = mt*16 + lg*4 + r;
                net[mt][r] += dacc[mt][r] + xs[row][0]*wc0 + xs[row][1]*wc1
                              + xs[row][2]*wc2 + ccv;
            }
    }

    {
        float gc = gO[col], bcv = bO[col], wo = Wo[col];
        #pragma unroll
        for (int mt = 0; mt < 2; ++mt)
            #pragma unroll
            for (int r = 0; r < 4; ++r) {
                int row = mt*16 + lg*4 + r;
                actO[row][col] = fmaxf(net[mt][r]*gc + bcv, 0.0f) * wo;
            }
    }
    __syncthreads();
    if (t < FRAME_K) {
        float s = 0.0f;
        for (int d = 0; d < HID; d += 4) {
            float4 a4 = *reinterpret_cast<const float4*>(&actO[t][d]);
            s += a4.x + a4.y + a4.z + a4.w;
        }
        float gp = s + bo[0];
        float e = gtv[m*FRAME_K + t] - gp;
        rsum[t] = e*e;
    }
    __syncthreads();
    if (t == 0) {
        float s = 0.0f;
        #pragma unroll
        for (int j = 0; j < FRAME_K; ++j) s += rsum[j];
        loss_part[m] = s;
    }
}

// ---------------- K4: final reduction -------------------------------------
__global__ __launch_bounds__(256) void k_loss(
    const float* __restrict__ lp, float* __restrict__ out)
{
    __shared__ float red[256];
    int t = threadIdx.x;
    red[t] = lp[t] + lp[t+256];
    __syncthreads();
    for (int s = 128; s > 0; s >>= 1) {
        if (t < s) red[t] += red[t+s];
        __syncthreads();
    }
    if (t == 0) out[0] = red[0] * (50.0f / 16384.0f);
}

extern "C" void kernel_launch(void* const* d_in, const int* in_sizes, int n_in,
                              void* d_out, int out_size, void* d_ws, size_t ws_size,
                              hipStream_t stream)
{
    (void)in_sizes; (void)n_in; (void)out_size; (void)ws_size;
    const float* pcl_noisy = (const float*)d_in[0];
    const float* pcl_clean = (const float*)d_in[1];
    const int*   pnt_idx   = (const int*)d_in[2];
    const float* feW1 = (const float*)d_in[3];
    const float* feb1 = (const float*)d_in[4];
    const float* feW2 = (const float*)d_in[5];
    const float* feb2 = (const float*)d_in[6];
    const float* Wp  = (const float*)d_in[7];
    const float* bp  = (const float*)d_in[8];
    const float* g0  = (const float*)d_in[9];
    const float* b0  = (const float*)d_in[10];
    const float* W0  = (const float*)d_in[11];
    const float* bf0 = (const float*)d_in[12];
    const float* g1  = (const float*)d_in[13];
    const float* b1  = (const float*)d_in[14];
    const float* W1  = (const float*)d_in[15];
    const float* bf1 = (const float*)d_in[16];
    const float* Wc  = (const float*)d_in[17];
    const float* bc  = (const float*)d_in[18];
    const float* gO  = (const float*)d_in[19];
    const float* bO  = (const float*)d_in[20];
    const float* Wo  = (const float*)d_in[21];
    const float* bo  = (const float*)d_in[22];

    float* ws = (float*)d_ws;
    float* feat    = ws;                       // 65536 floats
    float* frames  = ws + 65536;               // 49152
    float* framesC = ws + 65536 + 49152;       // 49152
    float* gt      = ws + 163840;              // 16384
    float* lp      = ws + 180224;              // 512
    unsigned short* W0T = (unsigned short*)(ws + 180736);            // 65536 u16 (32768 floats)
    unsigned short* W1T = (unsigned short*)(ws + 180736 + 32768);    // 65536 u16
    float2* CXY = (float2*)(ws + 246272);      // 18000 float2 (36000 floats)
    float*  CZ  = ws + 282272;                 // 18000 floats -> ends 300272

    k_prep  <<<256, 256, 0, stream>>>(W0, W1, pcl_clean, W0T, W1T, CXY, CZ);
    k_nbr   <<<512, 256, 0, stream>>>(pcl_noisy, pnt_idx, feW1, feb1, feW2, feb2,
                                      feat, frames, framesC);
    k_clean <<<4096, 256, 0, stream>>>(CXY, CZ, frames, gt);
    k_score <<<512, 512, 0, stream>>>(feat, framesC, gt, W0T, W1T,
                                      Wp, bp, g0, b0, bf0, g1, b1, bf1,
                                      Wc, bc, gO, bO, Wo, bo, lp);
    k_loss  <<<1, 256, 0, stream>>>(lp, (float*)d_out);
}